// Round 8
// baseline (612.121 us; speedup 1.0000x reference)
//
#include <hip/hip_runtime.h>
#include <math.h>

#define HID 4096
#define CDIM 256
#define KCB 4096
#define NTOK 16384

// ---------------- ws layout ----------------
// floats:
//   z:    [0, 4194304)
//   e2:   [4194304, 4198400)
//   idx:  [4198400, 4214784)  (int32)
//   logz: [4214784]
//   part: [4214785, 4215809)
//   cval: [4215812, 4281348)   4 chunks x 16384
//   cidx: [4281348, 4346884)   (int32)
// shorts (bf16 bits) from float-offset CBS_OFF (byte 17387536, 16B aligned):
//   s1h/s1m/s1l  [1048576 each]  -- W_pre h/m splits, then W_post h/m
//   cbh/cbm/cbl  [1048576 each]  -- codebook splits (argmin needs 6-product)
#define Z_OFF    0
#define E2_OFF   4194304
#define IDX_OFF  4198400
#define LOGZ_OFF 4214784
#define PART_OFF 4214785
#define CVAL_OFF 4215812
#define CIDX_OFF 4281348
#define CBS_OFF  4346884

// d_out layout (floats): embed_hat [0,67108864) | bits | vq_loss | idx(float) x 16384
#define OUT_BITS 67108864
#define OUT_VQ   67108865
#define OUT_IDX  67108866

typedef __attribute__((ext_vector_type(8))) short bf16x8;
typedef __attribute__((ext_vector_type(4))) float f32x4;
#define MFMA16(a, b, c) __builtin_amdgcn_mfma_f32_16x16x32_bf16(a, b, c, 0, 0, 0)

// shorts per one staging buffer: 3-split = 48KB, 2-split = 32KB
#define BUFSH  24576
#define BUFSH2 16384

__device__ __forceinline__ short f2bf(float v) {
  unsigned u = __float_as_uint(v);
  unsigned r = (u + 0x7FFFu + ((u >> 16) & 1u)) >> 16;
  return (short)r;
}
__device__ __forceinline__ float bf2f(short s) {
  return __uint_as_float(((unsigned)(unsigned short)s) << 16);
}

__device__ __forceinline__ void gld_lds16(const void* g, void* l) {
  __builtin_amdgcn_global_load_lds(
      (const __attribute__((address_space(1))) unsigned*)g,
      (__attribute__((address_space(3))) unsigned*)l, 16, 0, 0);
}

// Stage one 32-col x 256-k x 3-split bf16 tile (48KB) with 512 threads.
// Source row stride = 1<<rowshift bytes, k-window at byte offset kbyte.
// LDS (col,ch) holds global chunk ch^(col&7); reads at byte
// ((col<<9)+kbyte')^((col&7)<<4). Same data layout as R3-R7 (bit-identical).
__device__ __forceinline__ void stage512(const short* g0, const short* g1,
                                         const short* g2, int rowshift, int n0,
                                         int kbyte, int t, short* lds) {
  const short* gs[3] = {g0, g1, g2};
  int tw = t & 448;  // wave-uniform base
#pragma unroll
  for (int s = 0; s < 3; ++s) {
    const char* gb = (const char*)gs[s];
#pragma unroll
    for (int j = 0; j < 2; ++j) {
      int c0 = j * 512 + t;           // chunk id 0..1023
      int col = c0 >> 5;
      int sch = (c0 & 31) ^ (col & 7);
      const char* src = gb + ((size_t)(n0 + col) << rowshift) + kbyte +
                        ((size_t)sch << 4);
      short* dst = lds + (size_t)s * 8192 + (size_t)(j * 512 + tw) * 8;
      gld_lds16(src, dst);
    }
  }
}

// 2-split variant (32KB tile): splits h,m only.
__device__ __forceinline__ void stage512_2(const short* g0, const short* g1,
                                           int rowshift, int n0, int kbyte,
                                           int t, short* lds) {
  const short* gs[2] = {g0, g1};
  int tw = t & 448;
#pragma unroll
  for (int s = 0; s < 2; ++s) {
    const char* gb = (const char*)gs[s];
#pragma unroll
    for (int j = 0; j < 2; ++j) {
      int c0 = j * 512 + t;
      int col = c0 >> 5;
      int sch = (c0 & 31) ^ (col & 7);
      const char* src = gb + ((size_t)(n0 + col) << rowshift) + kbyte +
                        ((size_t)sch << 4);
      short* dst = lds + (size_t)s * 8192 + (size_t)(j * 512 + tw) * 8;
      gld_lds16(src, dst);
    }
  }
}

// ---------------- small kernels ----------------

__global__ void k_e2(const float* __restrict__ cb, float* __restrict__ e2) {
  int row = blockIdx.x * 4 + (threadIdx.x >> 6);
  int lane = threadIdx.x & 63;
  float4 v = ((const float4*)(cb + (size_t)row * CDIM))[lane];
  float s = v.x * v.x + v.y * v.y + v.z * v.z + v.w * v.w;
#pragma unroll
  for (int off = 32; off; off >>= 1) s += __shfl_down(s, off, 64);
  if (lane == 0) e2[row] = s;
}

__global__ void k_logz(const float* __restrict__ pl, float* __restrict__ logz) {
  __shared__ float red[8];
  int t = threadIdx.x;
  float mx = -INFINITY;
  for (int q = t; q < KCB; q += 256) mx = fmaxf(mx, pl[q]);
#pragma unroll
  for (int off = 32; off; off >>= 1) mx = fmaxf(mx, __shfl_down(mx, off, 64));
  if ((t & 63) == 0) red[t >> 6] = mx;
  __syncthreads();
  mx = fmaxf(fmaxf(red[0], red[1]), fmaxf(red[2], red[3]));
  float s = 0.f;
  for (int q = t; q < KCB; q += 256) s += expf(pl[q] - mx);
#pragma unroll
  for (int off = 32; off; off >>= 1) s += __shfl_down(s, off, 64);
  if ((t & 63) == 0) red[4 + (t >> 6)] = s;
  __syncthreads();
  if (t == 0) logz[0] = mx + logf(red[4] + red[5] + red[6] + red[7]);
}

// split fp32 -> 3x bf16 (h/m/l); 1048576 elements (codebook only)
__global__ void k_split3(const float* __restrict__ src, short* __restrict__ ch,
                         short* __restrict__ cm, short* __restrict__ cl) {
  int g = blockIdx.x * 256 + threadIdx.x;
  float4 v = ((const float4*)src)[g];
  float vv[4] = {v.x, v.y, v.z, v.w};
  short h[4], m[4], l[4];
#pragma unroll
  for (int i = 0; i < 4; ++i) {
    float x = vv[i];
    short hb = f2bf(x);
    float r1 = x - bf2f(hb);
    short mb = f2bf(r1);
    float r2 = r1 - bf2f(mb);
    short lb = f2bf(r2);
    h[i] = hb; m[i] = mb; l[i] = lb;
  }
  *(short4*)(ch + (size_t)g * 4) = make_short4(h[0], h[1], h[2], h[3]);
  *(short4*)(cm + (size_t)g * 4) = make_short4(m[0], m[1], m[2], m[3]);
  *(short4*)(cl + (size_t)g * 4) = make_short4(l[0], l[1], l[2], l[3]);
}

// split fp32 -> 2x bf16 (h/m); 1048576 elements (W_pre and W_post)
__global__ void k_split2(const float* __restrict__ src, short* __restrict__ ch,
                         short* __restrict__ cm) {
  int g = blockIdx.x * 256 + threadIdx.x;
  float4 v = ((const float4*)src)[g];
  float vv[4] = {v.x, v.y, v.z, v.w};
  short h[4], m[4];
#pragma unroll
  for (int i = 0; i < 4; ++i) {
    float x = vv[i];
    short hb = f2bf(x);
    float r1 = x - bf2f(hb);   // exact (Sterbenz)
    m[i] = f2bf(r1);
    h[i] = hb;
  }
  *(short4*)(ch + (size_t)g * 4) = make_short4(h[0], h[1], h[2], h[3]);
  *(short4*)(cm + (size_t)g * 4) = make_short4(m[0], m[1], m[2], m[3]);
}

// ---------------- GEMM1 via 2-split/4-product MFMA: z = embed @ W_pre^T + b ----------------
// R8 CHANGE (scheduling only, z bit-identical to R7): A window held in 64
// VGPR; km+1's global loads issued during the ti==1 MFMA phase (T14 split),
// one full MFMA phase + barrier ahead of the split that consumes them.

__launch_bounds__(512, 2)
__global__ void k_pre_mfma(const float* __restrict__ A,
                           const short* __restrict__ wh,
                           const short* __restrict__ wm,
                           const float* __restrict__ bias,
                           float* __restrict__ Cm) {
  __shared__ __align__(16) short Bsh[2 * BUFSH2];
  int bid = blockIdx.x;
  int work = (bid & 7) * 64 + (bid >> 3);   // bijective, 512 % 8 == 0
  int rg = work >> 2, ng = work & 3;
  int t = threadIdx.x;
  int wid = t >> 6, lane = t & 63;
  int m0 = rg * 128 + wid * 16;
  int l15 = lane & 15, lg = lane >> 4;

  f32x4 acc[2][2];
#pragma unroll
  for (int ti = 0; ti < 2; ++ti)
#pragma unroll
    for (int nf = 0; nf < 2; ++nf) acc[ti][nf] = (f32x4){0.f, 0.f, 0.f, 0.f};

  const float* abase = A + (size_t)(m0 + l15) * HID + lg * 8;

  // prefetch A window km=0 into registers
  float4 a0b[8], a1b[8];
#pragma unroll
  for (int ks = 0; ks < 8; ++ks) {
    a0b[ks] = *(const float4*)(abase + ks * 32);
    a1b[ks] = *(const float4*)(abase + ks * 32 + 4);
  }

  // prologue: stage tile 0
  stage512_2(wh, wm, 13, ng * 64, 0, t, Bsh);
  __syncthreads();

  bf16x8 zh[8], zm[8];
  for (int tt = 0; tt < 32; ++tt) {
    int km = tt >> 1, ti = tt & 1;
    if (tt + 1 < 32) {
      int km2 = (tt + 1) >> 1, ti2 = (tt + 1) & 1;
      stage512_2(wh, wm, 13, ng * 64 + ti2 * 32, km2 * 512, t,
                 Bsh + ((tt + 1) & 1) * BUFSH2);
    }
    if (ti == 0) {
      // split prefetched A window (registers) -> zh/zm (sequence = R7)
#pragma unroll
      for (int ks = 0; ks < 8; ++ks) {
        float v[8] = {a0b[ks].x, a0b[ks].y, a0b[ks].z, a0b[ks].w,
                      a1b[ks].x, a1b[ks].y, a1b[ks].z, a1b[ks].w};
#pragma unroll
        for (int i = 0; i < 8; ++i) {
          float x = v[i];
          short hb = f2bf(x);
          float r1 = x - bf2f(hb);
          zh[ks][i] = hb;
          zm[ks][i] = f2bf(r1);
        }
      }
    } else if (km + 1 < 16) {
      // issue km+1's A loads; consumed at tt+1's split (one MFMA phase away)
      const float* arow = abase + (km + 1) * 256;
#pragma unroll
      for (int ks = 0; ks < 8; ++ks) {
        a0b[ks] = *(const float4*)(arow + ks * 32);
        a1b[ks] = *(const float4*)(arow + ks * 32 + 4);
      }
    }
    const char* bufb = (const char*)(Bsh + (tt & 1) * BUFSH2);
#pragma unroll
    for (int ks = 0; ks < 8; ++ks) {
#pragma unroll
      for (int nf = 0; nf < 2; ++nf) {
        int col32 = nf * 16 + l15;
        int byte = ((col32 << 9) + ks * 64 + lg * 16) ^ ((col32 & 7) << 4);
        const char* base = bufb + byte;
        bf16x8 bh = *(const bf16x8*)(base);
        bf16x8 bm = *(const bf16x8*)(base + 16384);
        acc[ti][nf] = MFMA16(zh[ks], bh, acc[ti][nf]);
        acc[ti][nf] = MFMA16(zh[ks], bm, acc[ti][nf]);
        acc[ti][nf] = MFMA16(zm[ks], bh, acc[ti][nf]);
        acc[ti][nf] = MFMA16(zm[ks], bm, acc[ti][nf]);
      }
    }
    __syncthreads();
  }
#pragma unroll
  for (int ti = 0; ti < 2; ++ti)
#pragma unroll
    for (int nf = 0; nf < 2; ++nf) {
      int col = ng * 64 + ti * 32 + nf * 16 + l15;
      float bv = bias[col];
#pragma unroll
      for (int r = 0; r < 4; ++r) {
        Cm[(size_t)(m0 + lg * 4 + r) * CDIM + col] = acc[ti][nf][r] + bv;
      }
    }
}

// ---------------- argmin via 6-product split MFMA, dbuf (UNCHANGED — must stay
// 6-product: dist must land on numpy's fp32 grid, ties resolved by index) ----

__launch_bounds__(512, 2)
__global__ void k_argmin_mfma(const float* __restrict__ Z,
                              const short* __restrict__ cbh,
                              const short* __restrict__ cbm,
                              const short* __restrict__ cbl,
                              const float* __restrict__ e2,
                              float* __restrict__ cval, int* __restrict__ cidx) {
  __shared__ __align__(16) short Bsh[2 * BUFSH];
  int bid = blockIdx.x;
  int work = (bid & 7) * 64 + (bid >> 3);
  int chunk = work >> 7, rg = work & 127;
  int t = threadIdx.x;
  int wid = t >> 6, lane = t & 63;
  int m0 = rg * 128 + wid * 16;
  int l15 = lane & 15, lg = lane >> 4;

  stage512(cbh, cbm, cbl, 9, chunk * 1024, 0, t, Bsh);

  bf16x8 zh[8], zm[8], zl[8];
  float sq[8];
  const float* zrow = Z + (size_t)(m0 + l15) * CDIM + lg * 8;
#pragma unroll
  for (int ks = 0; ks < 8; ++ks) {
    float4 a0 = *(const float4*)(zrow + ks * 32);
    float4 a1 = *(const float4*)(zrow + ks * 32 + 4);
    float v[8] = {a0.x, a0.y, a0.z, a0.w, a1.x, a1.y, a1.z, a1.w};
#pragma unroll
    for (int i = 0; i < 8; ++i) {
      float x = v[i];
      short hb = f2bf(x);
      float r1 = x - bf2f(hb);
      short mb = f2bf(r1);
      float r2 = r1 - bf2f(mb);
      short lb = f2bf(r2);
      zh[ks][i] = hb; zm[ks][i] = mb; zl[ks][i] = lb;
    }
    sq[ks] = ((v[0] * v[0] + v[1] * v[1]) + (v[2] * v[2] + v[3] * v[3])) +
             ((v[4] * v[4] + v[5] * v[5]) + (v[6] * v[6] + v[7] * v[7]));
  }
  float x2p = ((sq[0] + sq[1]) + (sq[2] + sq[3])) + ((sq[4] + sq[5]) + (sq[6] + sq[7]));
  x2p += __shfl_xor(x2p, 16);
  x2p += __shfl_xor(x2p, 32);
  float x2r[4];
#pragma unroll
  for (int r = 0; r < 4; ++r) x2r[r] = __shfl(x2p, lg * 4 + r, 64);

  float bestv[4] = {INFINITY, INFINITY, INFINITY, INFINITY};
  int besti[4] = {0, 0, 0, 0};
  __syncthreads();  // tile 0 staged

  for (int st = 0; st < 32; ++st) {
    int n0 = chunk * 1024 + st * 32;
    float e2a = e2[n0 + l15];
    float e2b = e2[n0 + 16 + l15];
    if (st + 1 < 32)
      stage512(cbh, cbm, cbl, 9, chunk * 1024 + (st + 1) * 32, 0, t,
               Bsh + ((st + 1) & 1) * BUFSH);
    const char* bufb = (const char*)(Bsh + (st & 1) * BUFSH);
    f32x4 acc[2];
    acc[0] = (f32x4){0.f, 0.f, 0.f, 0.f};
    acc[1] = (f32x4){0.f, 0.f, 0.f, 0.f};
#pragma unroll
    for (int ks = 0; ks < 8; ++ks) {
#pragma unroll
      for (int nf = 0; nf < 2; ++nf) {
        int col32 = nf * 16 + l15;
        int byte = ((col32 << 9) + ks * 64 + lg * 16) ^ ((col32 & 7) << 4);
        const char* base = bufb + byte;
        bf16x8 bh = *(const bf16x8*)(base);
        bf16x8 bm = *(const bf16x8*)(base + 16384);
        bf16x8 bl = *(const bf16x8*)(base + 32768);
        acc[nf] = MFMA16(zh[ks], bh, acc[nf]);
        acc[nf] = MFMA16(zh[ks], bm, acc[nf]);
        acc[nf] = MFMA16(zm[ks], bh, acc[nf]);
        acc[nf] = MFMA16(zm[ks], bm, acc[nf]);
        acc[nf] = MFMA16(zh[ks], bl, acc[nf]);
        acc[nf] = MFMA16(zl[ks], bh, acc[nf]);
      }
    }
#pragma unroll
    for (int nf = 0; nf < 2; ++nf) {
      int col = n0 + nf * 16 + l15;
      float e2v = nf ? e2b : e2a;
#pragma unroll
      for (int r = 0; r < 4; ++r) {
        float s = __fsub_rn(__fadd_rn(x2r[r], e2v), __fmul_rn(2.0f, acc[nf][r]));
        if (s < bestv[r]) { bestv[r] = s; besti[r] = col; }
      }
    }
    __syncthreads();
  }
#pragma unroll
  for (int r = 0; r < 4; ++r) {
    float v = bestv[r];
    int bi = besti[r];
#pragma unroll
    for (int off = 8; off; off >>= 1) {
      float ov = __shfl_down(v, off, 16);
      int oi = __shfl_down(bi, off, 16);
      if (ov < v || (ov == v && oi < bi)) { v = ov; bi = oi; }
    }
    if (l15 == 0) {
      int row = m0 + lg * 4 + r;
      cval[chunk * NTOK + row] = v;
      cidx[chunk * NTOK + row] = bi;
    }
  }
}

// merge 4 chunk candidates per row (UNCHANGED)
__global__ void k_merge(const float* __restrict__ cval, const int* __restrict__ cidx,
                        int* __restrict__ idx_out, float* __restrict__ idx_f) {
  int r = blockIdx.x * 256 + threadIdx.x;
  float v = cval[r];
  int bi = cidx[r];
#pragma unroll
  for (int c = 1; c < 4; ++c) {
    float ov = cval[c * NTOK + r];
    int oi = cidx[c * NTOK + r];
    if (ov < v || (ov == v && oi < bi)) { v = ov; bi = oi; }
  }
  idx_out[r] = bi;
  idx_f[r] = (float)bi;
}

// ---------------- GEMM3 via 2-split/4-product MFMA ----------------
// R8 CHANGE (provably safe): embed_hat via h/m 2-split, products hh,hm,mh,mm.
// delta ~2e-8 << passing 3.8e-6 margin; idx path untouched.

__launch_bounds__(512, 2)
__global__ void k_post_mfma(const float* __restrict__ CB, const int* __restrict__ idx,
                            const short* __restrict__ wh, const short* __restrict__ wm,
                            const float* __restrict__ bias, float* __restrict__ out) {
  __shared__ __align__(16) short Bsh[2 * BUFSH2];
  int bid = blockIdx.x;
  int work = (bid & 7) * 64 + (bid >> 3);
  int chunk = work >> 7, rg = work & 127;
  int t = threadIdx.x;
  int wid = t >> 6, lane = t & 63;
  int m0 = rg * 128 + wid * 16;
  int l15 = lane & 15, lg = lane >> 4;

  stage512_2(wh, wm, 9, chunk * 1024, 0, t, Bsh);

  int code = idx[m0 + l15];
  const float* arow = CB + (size_t)code * CDIM + lg * 8;
  bf16x8 ah[8], am[8];
#pragma unroll
  for (int ks = 0; ks < 8; ++ks) {
    float4 a0 = *(const float4*)(arow + ks * 32);
    float4 a1 = *(const float4*)(arow + ks * 32 + 4);
    float v[8] = {a0.x, a0.y, a0.z, a0.w, a1.x, a1.y, a1.z, a1.w};
#pragma unroll
    for (int i = 0; i < 8; ++i) {
      float x = v[i];
      short hb = f2bf(x);
      float r1 = x - bf2f(hb);
      ah[ks][i] = hb;
      am[ks][i] = f2bf(r1);
    }
  }
  __syncthreads();  // tile 0 staged

  for (int st = 0; st < 32; ++st) {
    int n0 = chunk * 1024 + st * 32;
    float bva = bias[n0 + l15];
    float bvb = bias[n0 + 16 + l15];
    if (st + 1 < 32)
      stage512_2(wh, wm, 9, chunk * 1024 + (st + 1) * 32, 0, t,
                 Bsh + ((st + 1) & 1) * BUFSH2);
    const char* bufb = (const char*)(Bsh + (st & 1) * BUFSH2);
    f32x4 acc[2];
    acc[0] = (f32x4){0.f, 0.f, 0.f, 0.f};
    acc[1] = (f32x4){0.f, 0.f, 0.f, 0.f};
#pragma unroll
    for (int ks = 0; ks < 8; ++ks) {
#pragma unroll
      for (int nf = 0; nf < 2; ++nf) {
        int col32 = nf * 16 + l15;
        int byte = ((col32 << 9) + ks * 64 + lg * 16) ^ ((col32 & 7) << 4);
        const char* base = bufb + byte;
        bf16x8 bh = *(const bf16x8*)(base);
        bf16x8 bm = *(const bf16x8*)(base + 16384);
        acc[nf] = MFMA16(ah[ks], bh, acc[nf]);
        acc[nf] = MFMA16(ah[ks], bm, acc[nf]);
        acc[nf] = MFMA16(am[ks], bh, acc[nf]);
        acc[nf] = MFMA16(am[ks], bm, acc[nf]);
      }
    }
#pragma unroll
    for (int nf = 0; nf < 2; ++nf) {
      int col = n0 + nf * 16 + l15;
      float bv = nf ? bvb : bva;
#pragma unroll
      for (int r = 0; r < 4; ++r) {
        out[(size_t)(m0 + lg * 4 + r) * HID + col] = acc[nf][r] + bv;
      }
    }
    __syncthreads();
  }
}

// ---------------- losses (UNCHANGED) ----------------

__global__ void k_loss(const float* __restrict__ Z, const float* __restrict__ CB,
                       const int* __restrict__ idx, float* __restrict__ part) {
  __shared__ float red[4];
  int t = threadIdx.x;
  int g = blockIdx.x * 256 + t;
  int n = g >> 4;
  int d0 = (g & 15) << 4;
  const float4* zp = (const float4*)(Z + (size_t)n * CDIM + d0);
  const float4* cp = (const float4*)(CB + (size_t)idx[n] * CDIM + d0);
  float s = 0.f;
#pragma unroll
  for (int q = 0; q < 4; ++q) {
    float4 a = zp[q], b = cp[q];
    float dx = a.x - b.x, dy = a.y - b.y, dz = a.z - b.z, dw = a.w - b.w;
    s += dx * dx + dy * dy + dz * dz + dw * dw;
  }
#pragma unroll
  for (int off = 32; off; off >>= 1) s += __shfl_down(s, off, 64);
  if ((t & 63) == 0) red[t >> 6] = s;
  __syncthreads();
  if (t == 0) part[blockIdx.x] = red[0] + red[1] + red[2] + red[3];
}

__global__ void k_final(const float* __restrict__ part, const int* __restrict__ idx,
                        const float* __restrict__ pl, const float* __restrict__ logz,
                        float* __restrict__ bits_out, float* __restrict__ vq_out) {
  __shared__ float red[8];
  int t = threadIdx.x;
  float s = 0.f;
  for (int q = t; q < 1024; q += 256) s += part[q];
#pragma unroll
  for (int off = 32; off; off >>= 1) s += __shfl_down(s, off, 64);
  if ((t & 63) == 0) red[t >> 6] = s;
  __syncthreads();
  float S = red[0] + red[1] + red[2] + red[3];
  float lz = logz[0];
  float b = 0.f;
  for (int q = t; q < NTOK; q += 256) b += (lz - pl[idx[q]]);
#pragma unroll
  for (int off = 32; off; off >>= 1) b += __shfl_down(b, off, 64);
  if ((t & 63) == 0) red[4 + (t >> 6)] = b;
  __syncthreads();
  if (t == 0) {
    float Bsum = red[4] + red[5] + red[6] + red[7];
    float m = S / 4194304.0f;
    vq_out[0] = __fadd_rn(m, __fmul_rn(0.25f, m));
    bits_out[0] = Bsum / 0.69314718055994531f;
  }
}

// ---------------- launch ----------------

extern "C" void kernel_launch(void* const* d_in, const int* in_sizes, int n_in,
                              void* d_out, int out_size, void* d_ws, size_t ws_size,
                              hipStream_t stream) {
  const float* embed    = (const float*)d_in[0];
  const float* W_pre    = (const float*)d_in[1];
  const float* b_pre    = (const float*)d_in[2];
  const float* codebook = (const float*)d_in[3];
  const float* W_post   = (const float*)d_in[4];
  const float* b_post   = (const float*)d_in[5];
  const float* prior    = (const float*)d_in[6];

  float* out = (float*)d_out;
  float* ws  = (float*)d_ws;
  float* z    = ws + Z_OFF;
  float* e2   = ws + E2_OFF;
  int*   idxw = (int*)(ws + IDX_OFF);
  float* logz = ws + LOGZ_OFF;
  float* part = ws + PART_OFF;
  float* cval = ws + CVAL_OFF;
  int*   cidx = (int*)(ws + CIDX_OFF);
  short* s1h  = (short*)(ws + CBS_OFF);       // W_pre h/m; later W_post h/m
  short* s1m  = s1h + (size_t)KCB * CDIM;
  short* s1l  = s1m + (size_t)KCB * CDIM;     // unused this round (kept for layout)
  short* cbh  = s1l + (size_t)KCB * CDIM;     // codebook splits
  short* cbm  = cbh + (size_t)KCB * CDIM;
  short* cbl  = cbm + (size_t)KCB * CDIM;

  k_e2<<<dim3(1024), dim3(256), 0, stream>>>(codebook, e2);
  k_logz<<<dim3(1), dim3(256), 0, stream>>>(prior, logz);
  k_split2<<<dim3(1024), dim3(256), 0, stream>>>(W_pre, s1h, s1m);
  k_split3<<<dim3(1024), dim3(256), 0, stream>>>(codebook, cbh, cbm, cbl);
  k_pre_mfma<<<dim3(512), dim3(512), 0, stream>>>(embed, s1h, s1m, b_pre, z);
  k_argmin_mfma<<<dim3(512), dim3(512), 0, stream>>>(z, cbh, cbm, cbl, e2, cval, cidx);
  k_merge<<<dim3(64), dim3(256), 0, stream>>>(cval, cidx, idxw, out + OUT_IDX);
  // reuse s1h/s1m for W_post splits (W_pre splits dead after k_pre_mfma)
  k_split2<<<dim3(1024), dim3(256), 0, stream>>>(W_post, s1h, s1m);
  k_post_mfma<<<dim3(512), dim3(512), 0, stream>>>(codebook, idxw, s1h, s1m,
                                                   b_post, out);
  k_loss<<<dim3(1024), dim3(256), 0, stream>>>(z, codebook, idxw, part);
  k_final<<<dim3(1), dim3(256), 0, stream>>>(part, idxw, prior, logz,
                                             out + OUT_BITS, out + OUT_VQ);
}

// Round 9
// 531.225 us; speedup vs baseline: 1.1523x; 1.1523x over previous
//
#include <hip/hip_runtime.h>
#include <math.h>

#define HID 4096
#define CDIM 256
#define KCB 4096
#define NTOK 16384

// ---------------- ws layout ----------------
// floats:
//   z:    [0, 4194304)
//   e2:   [4194304, 4198400)
//   idx:  [4198400, 4214784)  (int32)
//   logz: [4214784]
//   part: [4214785, 4215809)
//   cval: [4215812, 4281348)   4 chunks x 16384
//   cidx: [4281348, 4346884)   (int32)
// shorts (bf16 bits) from float-offset CBS_OFF (byte 17387536, 16B aligned):
//   s1h/s1m/s1l  [1048576 each]  -- W_pre h/m splits, then W_post h/m
//   cbh/cbm/cbl  [1048576 each]  -- codebook splits (argmin needs 6-product)
#define Z_OFF    0
#define E2_OFF   4194304
#define IDX_OFF  4198400
#define LOGZ_OFF 4214784
#define PART_OFF 4214785
#define CVAL_OFF 4215812
#define CIDX_OFF 4281348
#define CBS_OFF  4346884

// d_out layout (floats): embed_hat [0,67108864) | bits | vq_loss | idx(float) x 16384
#define OUT_BITS 67108864
#define OUT_VQ   67108865
#define OUT_IDX  67108866

typedef __attribute__((ext_vector_type(8))) short bf16x8;
typedef __attribute__((ext_vector_type(4))) float f32x4;
#define MFMA16(a, b, c) __builtin_amdgcn_mfma_f32_16x16x32_bf16(a, b, c, 0, 0, 0)

// shorts per one staging buffer: 3-split = 48KB, 2-split = 32KB
#define BUFSH  24576
#define BUFSH2 16384

__device__ __forceinline__ short f2bf(float v) {
  unsigned u = __float_as_uint(v);
  unsigned r = (u + 0x7FFFu + ((u >> 16) & 1u)) >> 16;
  return (short)r;
}
__device__ __forceinline__ float bf2f(short s) {
  return __uint_as_float(((unsigned)(unsigned short)s) << 16);
}

__device__ __forceinline__ void gld_lds16(const void* g, void* l) {
  __builtin_amdgcn_global_load_lds(
      (const __attribute__((address_space(1))) unsigned*)g,
      (__attribute__((address_space(3))) unsigned*)l, 16, 0, 0);
}

// Stage one 32-col x 256-k x 3-split bf16 tile (48KB) with 512 threads.
// Source row stride = 1<<rowshift bytes, k-window at byte offset kbyte.
// LDS (col,ch) holds global chunk ch^(col&7); reads at byte
// ((col<<9)+kbyte')^((col&7)<<4). Same data layout as R3-R8 (bit-identical).
__device__ __forceinline__ void stage512(const short* g0, const short* g1,
                                         const short* g2, int rowshift, int n0,
                                         int kbyte, int t, short* lds) {
  const short* gs[3] = {g0, g1, g2};
  int tw = t & 448;  // wave-uniform base
#pragma unroll
  for (int s = 0; s < 3; ++s) {
    const char* gb = (const char*)gs[s];
#pragma unroll
    for (int j = 0; j < 2; ++j) {
      int c0 = j * 512 + t;           // chunk id 0..1023
      int col = c0 >> 5;
      int sch = (c0 & 31) ^ (col & 7);
      const char* src = gb + ((size_t)(n0 + col) << rowshift) + kbyte +
                        ((size_t)sch << 4);
      short* dst = lds + (size_t)s * 8192 + (size_t)(j * 512 + tw) * 8;
      gld_lds16(src, dst);
    }
  }
}

// 2-split variant (32KB tile): splits h,m only.
__device__ __forceinline__ void stage512_2(const short* g0, const short* g1,
                                           int rowshift, int n0, int kbyte,
                                           int t, short* lds) {
  const short* gs[2] = {g0, g1};
  int tw = t & 448;
#pragma unroll
  for (int s = 0; s < 2; ++s) {
    const char* gb = (const char*)gs[s];
#pragma unroll
    for (int j = 0; j < 2; ++j) {
      int c0 = j * 512 + t;
      int col = c0 >> 5;
      int sch = (c0 & 31) ^ (col & 7);
      const char* src = gb + ((size_t)(n0 + col) << rowshift) + kbyte +
                        ((size_t)sch << 4);
      short* dst = lds + (size_t)s * 8192 + (size_t)(j * 512 + tw) * 8;
      gld_lds16(src, dst);
    }
  }
}

// ---------------- small kernels ----------------

__global__ void k_logz(const float* __restrict__ pl, float* __restrict__ logz) {
  __shared__ float red[8];
  int t = threadIdx.x;
  float mx = -INFINITY;
  for (int q = t; q < KCB; q += 256) mx = fmaxf(mx, pl[q]);
#pragma unroll
  for (int off = 32; off; off >>= 1) mx = fmaxf(mx, __shfl_down(mx, off, 64));
  if ((t & 63) == 0) red[t >> 6] = mx;
  __syncthreads();
  mx = fmaxf(fmaxf(red[0], red[1]), fmaxf(red[2], red[3]));
  float s = 0.f;
  for (int q = t; q < KCB; q += 256) s += expf(pl[q] - mx);
#pragma unroll
  for (int off = 32; off; off >>= 1) s += __shfl_down(s, off, 64);
  if ((t & 63) == 0) red[4 + (t >> 6)] = s;
  __syncthreads();
  if (t == 0) logz[0] = mx + logf(red[4] + red[5] + red[6] + red[7]);
}

// split fp32 -> 3x bf16 (h/m/l) AND e2 row sums (codebook only).
// Each 64-lane wave covers exactly one 256-elem row (4 elems/lane), so the
// e2 reduction replicates the old k_e2 bit-exactly (same per-lane elements,
// same sum expression, same shfl_down butterfly).
__global__ void k_split3(const float* __restrict__ src, short* __restrict__ ch,
                         short* __restrict__ cm, short* __restrict__ cl,
                         float* __restrict__ e2) {
  int t = threadIdx.x;
  int g = blockIdx.x * 256 + t;
  float4 v = ((const float4*)src)[g];
  float vv[4] = {v.x, v.y, v.z, v.w};
  short h[4], m[4], l[4];
#pragma unroll
  for (int i = 0; i < 4; ++i) {
    float x = vv[i];
    short hb = f2bf(x);
    float r1 = x - bf2f(hb);
    short mb = f2bf(r1);
    float r2 = r1 - bf2f(mb);
    short lb = f2bf(r2);
    h[i] = hb; m[i] = mb; l[i] = lb;
  }
  *(short4*)(ch + (size_t)g * 4) = make_short4(h[0], h[1], h[2], h[3]);
  *(short4*)(cm + (size_t)g * 4) = make_short4(m[0], m[1], m[2], m[3]);
  *(short4*)(cl + (size_t)g * 4) = make_short4(l[0], l[1], l[2], l[3]);
  // e2: wave reduction (bit-identical to old k_e2)
  float s = v.x * v.x + v.y * v.y + v.z * v.z + v.w * v.w;
#pragma unroll
  for (int off = 32; off; off >>= 1) s += __shfl_down(s, off, 64);
  if ((t & 63) == 0) e2[blockIdx.x * 4 + (t >> 6)] = s;
}

// split fp32 -> 2x bf16 (h/m); 1048576 elements (W_pre and W_post)
__global__ void k_split2(const float* __restrict__ src, short* __restrict__ ch,
                         short* __restrict__ cm) {
  int g = blockIdx.x * 256 + threadIdx.x;
  float4 v = ((const float4*)src)[g];
  float vv[4] = {v.x, v.y, v.z, v.w};
  short h[4], m[4];
#pragma unroll
  for (int i = 0; i < 4; ++i) {
    float x = vv[i];
    short hb = f2bf(x);
    float r1 = x - bf2f(hb);   // exact (Sterbenz)
    m[i] = f2bf(r1);
    h[i] = hb;
  }
  *(short4*)(ch + (size_t)g * 4) = make_short4(h[0], h[1], h[2], h[3]);
  *(short4*)(cm + (size_t)g * 4) = make_short4(m[0], m[1], m[2], m[3]);
}

// ---------------- GEMM1 via 2-split/4-product MFMA: z = embed @ W_pre^T + b ----------------
// R9: reverted to the R7 body (64 VGPR, no register prefetch). R8's prefetch
// raised VGPR to 120 -> occupancy 39->23% -> 220->300us. Wave count beats
// latency hiding here; do not re-add without checking VGPR tier.

__launch_bounds__(512, 2)
__global__ void k_pre_mfma(const float* __restrict__ A,
                           const short* __restrict__ wh,
                           const short* __restrict__ wm,
                           const float* __restrict__ bias,
                           float* __restrict__ Cm) {
  __shared__ __align__(16) short Bsh[2 * BUFSH2];
  int bid = blockIdx.x;
  int work = (bid & 7) * 64 + (bid >> 3);   // bijective, 512 % 8 == 0
  int rg = work >> 2, ng = work & 3;
  int t = threadIdx.x;
  int wid = t >> 6, lane = t & 63;
  int m0 = rg * 128 + wid * 16;
  int l15 = lane & 15, lg = lane >> 4;

  f32x4 acc[2][2];
#pragma unroll
  for (int ti = 0; ti < 2; ++ti)
#pragma unroll
    for (int nf = 0; nf < 2; ++nf) acc[ti][nf] = (f32x4){0.f, 0.f, 0.f, 0.f};

  // prologue: stage tile 0
  stage512_2(wh, wm, 13, ng * 64, 0, t, Bsh);
  __syncthreads();

  bf16x8 zh[8], zm[8];
  for (int tt = 0; tt < 32; ++tt) {
    int km = tt >> 1, ti = tt & 1;
    if (tt + 1 < 32) {
      int km2 = (tt + 1) >> 1, ti2 = (tt + 1) & 1;
      stage512_2(wh, wm, 13, ng * 64 + ti2 * 32, km2 * 512, t,
                 Bsh + ((tt + 1) & 1) * BUFSH2);
    }
    if (ti == 0) {
      // A window [16 rows x 256 k] -> registers, 2-split h/m
      const float* arow = A + (size_t)(m0 + l15) * HID + km * 256 + lg * 8;
#pragma unroll
      for (int ks = 0; ks < 8; ++ks) {
        float4 a0 = *(const float4*)(arow + ks * 32);
        float4 a1 = *(const float4*)(arow + ks * 32 + 4);
        float v[8] = {a0.x, a0.y, a0.z, a0.w, a1.x, a1.y, a1.z, a1.w};
#pragma unroll
        for (int i = 0; i < 8; ++i) {
          float x = v[i];
          short hb = f2bf(x);
          float r1 = x - bf2f(hb);
          zh[ks][i] = hb;
          zm[ks][i] = f2bf(r1);
        }
      }
    }
    const char* bufb = (const char*)(Bsh + (tt & 1) * BUFSH2);
#pragma unroll
    for (int ks = 0; ks < 8; ++ks) {
#pragma unroll
      for (int nf = 0; nf < 2; ++nf) {
        int col32 = nf * 16 + l15;
        int byte = ((col32 << 9) + ks * 64 + lg * 16) ^ ((col32 & 7) << 4);
        const char* base = bufb + byte;
        bf16x8 bh = *(const bf16x8*)(base);
        bf16x8 bm = *(const bf16x8*)(base + 16384);
        acc[ti][nf] = MFMA16(zh[ks], bh, acc[ti][nf]);
        acc[ti][nf] = MFMA16(zh[ks], bm, acc[ti][nf]);
        acc[ti][nf] = MFMA16(zm[ks], bh, acc[ti][nf]);
        acc[ti][nf] = MFMA16(zm[ks], bm, acc[ti][nf]);
      }
    }
    __syncthreads();
  }
#pragma unroll
  for (int ti = 0; ti < 2; ++ti)
#pragma unroll
    for (int nf = 0; nf < 2; ++nf) {
      int col = ng * 64 + ti * 32 + nf * 16 + l15;
      float bv = bias[col];
#pragma unroll
      for (int r = 0; r < 4; ++r) {
        Cm[(size_t)(m0 + lg * 4 + r) * CDIM + col] = acc[ti][nf][r] + bv;
      }
    }
}

// ---------------- argmin via 6-product split MFMA, dbuf (UNCHANGED — must stay
// 6-product: dist must land on numpy's fp32 grid, ties resolved by index) ----

__launch_bounds__(512, 2)
__global__ void k_argmin_mfma(const float* __restrict__ Z,
                              const short* __restrict__ cbh,
                              const short* __restrict__ cbm,
                              const short* __restrict__ cbl,
                              const float* __restrict__ e2,
                              float* __restrict__ cval, int* __restrict__ cidx) {
  __shared__ __align__(16) short Bsh[2 * BUFSH];
  int bid = blockIdx.x;
  int work = (bid & 7) * 64 + (bid >> 3);
  int chunk = work >> 7, rg = work & 127;
  int t = threadIdx.x;
  int wid = t >> 6, lane = t & 63;
  int m0 = rg * 128 + wid * 16;
  int l15 = lane & 15, lg = lane >> 4;

  stage512(cbh, cbm, cbl, 9, chunk * 1024, 0, t, Bsh);

  bf16x8 zh[8], zm[8], zl[8];
  float sq[8];
  const float* zrow = Z + (size_t)(m0 + l15) * CDIM + lg * 8;
#pragma unroll
  for (int ks = 0; ks < 8; ++ks) {
    float4 a0 = *(const float4*)(zrow + ks * 32);
    float4 a1 = *(const float4*)(zrow + ks * 32 + 4);
    float v[8] = {a0.x, a0.y, a0.z, a0.w, a1.x, a1.y, a1.z, a1.w};
#pragma unroll
    for (int i = 0; i < 8; ++i) {
      float x = v[i];
      short hb = f2bf(x);
      float r1 = x - bf2f(hb);
      short mb = f2bf(r1);
      float r2 = r1 - bf2f(mb);
      short lb = f2bf(r2);
      zh[ks][i] = hb; zm[ks][i] = mb; zl[ks][i] = lb;
    }
    sq[ks] = ((v[0] * v[0] + v[1] * v[1]) + (v[2] * v[2] + v[3] * v[3])) +
             ((v[4] * v[4] + v[5] * v[5]) + (v[6] * v[6] + v[7] * v[7]));
  }
  float x2p = ((sq[0] + sq[1]) + (sq[2] + sq[3])) + ((sq[4] + sq[5]) + (sq[6] + sq[7]));
  x2p += __shfl_xor(x2p, 16);
  x2p += __shfl_xor(x2p, 32);
  float x2r[4];
#pragma unroll
  for (int r = 0; r < 4; ++r) x2r[r] = __shfl(x2p, lg * 4 + r, 64);

  float bestv[4] = {INFINITY, INFINITY, INFINITY, INFINITY};
  int besti[4] = {0, 0, 0, 0};
  __syncthreads();  // tile 0 staged

  for (int st = 0; st < 32; ++st) {
    int n0 = chunk * 1024 + st * 32;
    float e2a = e2[n0 + l15];
    float e2b = e2[n0 + 16 + l15];
    if (st + 1 < 32)
      stage512(cbh, cbm, cbl, 9, chunk * 1024 + (st + 1) * 32, 0, t,
               Bsh + ((st + 1) & 1) * BUFSH);
    const char* bufb = (const char*)(Bsh + (st & 1) * BUFSH);
    f32x4 acc[2];
    acc[0] = (f32x4){0.f, 0.f, 0.f, 0.f};
    acc[1] = (f32x4){0.f, 0.f, 0.f, 0.f};
#pragma unroll
    for (int ks = 0; ks < 8; ++ks) {
#pragma unroll
      for (int nf = 0; nf < 2; ++nf) {
        int col32 = nf * 16 + l15;
        int byte = ((col32 << 9) + ks * 64 + lg * 16) ^ ((col32 & 7) << 4);
        const char* base = bufb + byte;
        bf16x8 bh = *(const bf16x8*)(base);
        bf16x8 bm = *(const bf16x8*)(base + 16384);
        bf16x8 bl = *(const bf16x8*)(base + 32768);
        acc[nf] = MFMA16(zh[ks], bh, acc[nf]);
        acc[nf] = MFMA16(zh[ks], bm, acc[nf]);
        acc[nf] = MFMA16(zm[ks], bh, acc[nf]);
        acc[nf] = MFMA16(zm[ks], bm, acc[nf]);
        acc[nf] = MFMA16(zh[ks], bl, acc[nf]);
        acc[nf] = MFMA16(zl[ks], bh, acc[nf]);
      }
    }
#pragma unroll
    for (int nf = 0; nf < 2; ++nf) {
      int col = n0 + nf * 16 + l15;
      float e2v = nf ? e2b : e2a;
#pragma unroll
      for (int r = 0; r < 4; ++r) {
        float s = __fsub_rn(__fadd_rn(x2r[r], e2v), __fmul_rn(2.0f, acc[nf][r]));
        if (s < bestv[r]) { bestv[r] = s; besti[r] = col; }
      }
    }
    __syncthreads();
  }
#pragma unroll
  for (int r = 0; r < 4; ++r) {
    float v = bestv[r];
    int bi = besti[r];
#pragma unroll
    for (int off = 8; off; off >>= 1) {
      float ov = __shfl_down(v, off, 16);
      int oi = __shfl_down(bi, off, 16);
      if (ov < v || (ov == v && oi < bi)) { v = ov; bi = oi; }
    }
    if (l15 == 0) {
      int row = m0 + lg * 4 + r;
      cval[chunk * NTOK + row] = v;
      cidx[chunk * NTOK + row] = bi;
    }
  }
}

// merge 4 chunk candidates per row (UNCHANGED)
__global__ void k_merge(const float* __restrict__ cval, const int* __restrict__ cidx,
                        int* __restrict__ idx_out, float* __restrict__ idx_f) {
  int r = blockIdx.x * 256 + threadIdx.x;
  float v = cval[r];
  int bi = cidx[r];
#pragma unroll
  for (int c = 1; c < 4; ++c) {
    float ov = cval[c * NTOK + r];
    int oi = cidx[c * NTOK + r];
    if (ov < v || (ov == v && oi < bi)) { v = ov; bi = oi; }
  }
  idx_out[r] = bi;
  idx_f[r] = (float)bi;
}

// ---------------- GEMM3 via 2-split/4-product MFMA (UNCHANGED from R8) ----------------

__launch_bounds__(512, 2)
__global__ void k_post_mfma(const float* __restrict__ CB, const int* __restrict__ idx,
                            const short* __restrict__ wh, const short* __restrict__ wm,
                            const float* __restrict__ bias, float* __restrict__ out) {
  __shared__ __align__(16) short Bsh[2 * BUFSH2];
  int bid = blockIdx.x;
  int work = (bid & 7) * 64 + (bid >> 3);
  int chunk = work >> 7, rg = work & 127;
  int t = threadIdx.x;
  int wid = t >> 6, lane = t & 63;
  int m0 = rg * 128 + wid * 16;
  int l15 = lane & 15, lg = lane >> 4;

  stage512_2(wh, wm, 9, chunk * 1024, 0, t, Bsh);

  int code = idx[m0 + l15];
  const float* arow = CB + (size_t)code * CDIM + lg * 8;
  bf16x8 ah[8], am[8];
#pragma unroll
  for (int ks = 0; ks < 8; ++ks) {
    float4 a0 = *(const float4*)(arow + ks * 32);
    float4 a1 = *(const float4*)(arow + ks * 32 + 4);
    float v[8] = {a0.x, a0.y, a0.z, a0.w, a1.x, a1.y, a1.z, a1.w};
#pragma unroll
    for (int i = 0; i < 8; ++i) {
      float x = v[i];
      short hb = f2bf(x);
      float r1 = x - bf2f(hb);
      ah[ks][i] = hb;
      am[ks][i] = f2bf(r1);
    }
  }
  __syncthreads();  // tile 0 staged

  for (int st = 0; st < 32; ++st) {
    int n0 = chunk * 1024 + st * 32;
    float bva = bias[n0 + l15];
    float bvb = bias[n0 + 16 + l15];
    if (st + 1 < 32)
      stage512_2(wh, wm, 9, chunk * 1024 + (st + 1) * 32, 0, t,
                 Bsh + ((st + 1) & 1) * BUFSH2);
    const char* bufb = (const char*)(Bsh + (st & 1) * BUFSH2);
    f32x4 acc[2];
    acc[0] = (f32x4){0.f, 0.f, 0.f, 0.f};
    acc[1] = (f32x4){0.f, 0.f, 0.f, 0.f};
#pragma unroll
    for (int ks = 0; ks < 8; ++ks) {
#pragma unroll
      for (int nf = 0; nf < 2; ++nf) {
        int col32 = nf * 16 + l15;
        int byte = ((col32 << 9) + ks * 64 + lg * 16) ^ ((col32 & 7) << 4);
        const char* base = bufb + byte;
        bf16x8 bh = *(const bf16x8*)(base);
        bf16x8 bm = *(const bf16x8*)(base + 16384);
        acc[nf] = MFMA16(ah[ks], bh, acc[nf]);
        acc[nf] = MFMA16(ah[ks], bm, acc[nf]);
        acc[nf] = MFMA16(am[ks], bh, acc[nf]);
        acc[nf] = MFMA16(am[ks], bm, acc[nf]);
      }
    }
#pragma unroll
    for (int nf = 0; nf < 2; ++nf) {
      int col = n0 + nf * 16 + l15;
      float bv = nf ? bvb : bva;
#pragma unroll
      for (int r = 0; r < 4; ++r) {
        out[(size_t)(m0 + lg * 4 + r) * HID + col] = acc[nf][r] + bv;
      }
    }
    __syncthreads();
  }
}

// ---------------- losses (UNCHANGED) ----------------

__global__ void k_loss(const float* __restrict__ Z, const float* __restrict__ CB,
                       const int* __restrict__ idx, float* __restrict__ part) {
  __shared__ float red[4];
  int t = threadIdx.x;
  int g = blockIdx.x * 256 + t;
  int n = g >> 4;
  int d0 = (g & 15) << 4;
  const float4* zp = (const float4*)(Z + (size_t)n * CDIM + d0);
  const float4* cp = (const float4*)(CB + (size_t)idx[n] * CDIM + d0);
  float s = 0.f;
#pragma unroll
  for (int q = 0; q < 4; ++q) {
    float4 a = zp[q], b = cp[q];
    float dx = a.x - b.x, dy = a.y - b.y, dz = a.z - b.z, dw = a.w - b.w;
    s += dx * dx + dy * dy + dz * dz + dw * dw;
  }
#pragma unroll
  for (int off = 32; off; off >>= 1) s += __shfl_down(s, off, 64);
  if ((t & 63) == 0) red[t >> 6] = s;
  __syncthreads();
  if (t == 0) part[blockIdx.x] = red[0] + red[1] + red[2] + red[3];
}

__global__ void k_final(const float* __restrict__ part, const int* __restrict__ idx,
                        const float* __restrict__ pl, const float* __restrict__ logz,
                        float* __restrict__ bits_out, float* __restrict__ vq_out) {
  __shared__ float red[8];
  int t = threadIdx.x;
  float s = 0.f;
  for (int q = t; q < 1024; q += 256) s += part[q];
#pragma unroll
  for (int off = 32; off; off >>= 1) s += __shfl_down(s, off, 64);
  if ((t & 63) == 0) red[t >> 6] = s;
  __syncthreads();
  float S = red[0] + red[1] + red[2] + red[3];
  float lz = logz[0];
  float b = 0.f;
  for (int q = t; q < NTOK; q += 256) b += (lz - pl[idx[q]]);
#pragma unroll
  for (int off = 32; off; off >>= 1) b += __shfl_down(b, off, 64);
  if ((t & 63) == 0) red[4 + (t >> 6)] = b;
  __syncthreads();
  if (t == 0) {
    float Bsum = red[4] + red[5] + red[6] + red[7];
    float m = S / 4194304.0f;
    vq_out[0] = __fadd_rn(m, __fmul_rn(0.25f, m));
    bits_out[0] = Bsum / 0.69314718055994531f;
  }
}

// ---------------- launch ----------------

extern "C" void kernel_launch(void* const* d_in, const int* in_sizes, int n_in,
                              void* d_out, int out_size, void* d_ws, size_t ws_size,
                              hipStream_t stream) {
  const float* embed    = (const float*)d_in[0];
  const float* W_pre    = (const float*)d_in[1];
  const float* b_pre    = (const float*)d_in[2];
  const float* codebook = (const float*)d_in[3];
  const float* W_post   = (const float*)d_in[4];
  const float* b_post   = (const float*)d_in[5];
  const float* prior    = (const float*)d_in[6];

  float* out = (float*)d_out;
  float* ws  = (float*)d_ws;
  float* z    = ws + Z_OFF;
  float* e2   = ws + E2_OFF;
  int*   idxw = (int*)(ws + IDX_OFF);
  float* logz = ws + LOGZ_OFF;
  float* part = ws + PART_OFF;
  float* cval = ws + CVAL_OFF;
  int*   cidx = (int*)(ws + CIDX_OFF);
  short* s1h  = (short*)(ws + CBS_OFF);       // W_pre h/m; later W_post h/m
  short* s1m  = s1h + (size_t)KCB * CDIM;
  short* s1l  = s1m + (size_t)KCB * CDIM;     // spacer (layout unchanged)
  short* cbh  = s1l + (size_t)KCB * CDIM;     // codebook splits
  short* cbm  = cbh + (size_t)KCB * CDIM;
  short* cbl  = cbm + (size_t)KCB * CDIM;

  k_logz<<<dim3(1), dim3(256), 0, stream>>>(prior, logz);
  k_split2<<<dim3(1024), dim3(256), 0, stream>>>(W_pre, s1h, s1m);
  k_split3<<<dim3(1024), dim3(256), 0, stream>>>(codebook, cbh, cbm, cbl, e2);
  k_pre_mfma<<<dim3(512), dim3(512), 0, stream>>>(embed, s1h, s1m, b_pre, z);
  k_argmin_mfma<<<dim3(512), dim3(512), 0, stream>>>(z, cbh, cbm, cbl, e2, cval, cidx);
  k_merge<<<dim3(64), dim3(256), 0, stream>>>(cval, cidx, idxw, out + OUT_IDX);
  // reuse s1h/s1m for W_post splits (W_pre splits dead after k_pre_mfma)
  k_split2<<<dim3(1024), dim3(256), 0, stream>>>(W_post, s1h, s1m);
  k_post_mfma<<<dim3(512), dim3(512), 0, stream>>>(codebook, idxw, s1h, s1m,
                                                   b_post, out);
  k_loss<<<dim3(1024), dim3(256), 0, stream>>>(z, codebook, idxw, part);
  k_final<<<dim3(1), dim3(256), 0, stream>>>(part, idxw, prior, logz,
                                             out + OUT_BITS, out + OUT_VQ);
}